// Round 4
// baseline (77.169 us; speedup 1.0000x reference)
//
#include <hip/hip_runtime.h>
#include <hip/hip_bf16.h>

#define BSZ 16
#define TT 512
#define DD 512
#define MM (BSZ * TT)          // 8192 rows for the GEMM
#define NCB 4                  // N=512 / BN=128 col-blocks
#define NPART (NCB * 2)        // partial slices: col-block x col-half

#define NGEMM 256              // gemm role blocks in mega kernel (64 row-tiles x 4 col-tiles)
#define NLR   1024             // lr role blocks (16 batches x 64 row-groups)

typedef __attribute__((ext_vector_type(8))) short bf16x8;
typedef __attribute__((ext_vector_type(4))) float f32x4;

// ================= prep: convert_x + convert_w + cumsum in one launch =================
// grid: [0,4096) convert_x | [4096,4352) convert_w | [4352,4368) cumsum
__global__ __launch_bounds__(256) void prep_kernel(const float* __restrict__ x,
                                                   const float* __restrict__ W1,
                                                   const int* __restrict__ target,
                                                   ushort* __restrict__ xh,
                                                   ushort* __restrict__ xl,
                                                   ushort* __restrict__ wth,
                                                   ushort* __restrict__ wtl,
                                                   int* __restrict__ cs) {
    int bid = blockIdx.x;
    if (bid < 4096) {
        // ---- convert_x: x -> xh + xl (split bf16), 4 floats/thread ----
        int i = bid * 256 + threadIdx.x;
        float4 v = ((const float4*)x)[i];
        float f[4] = {v.x, v.y, v.z, v.w};
        ushort hh[4], ll[4];
        #pragma unroll
        for (int j = 0; j < 4; ++j) {
            __hip_bfloat16 bh = __float2bfloat16(f[j]);
            float r = f[j] - __bfloat162float(bh);
            __hip_bfloat16 bl = __float2bfloat16(r);
            hh[j] = *(ushort*)&bh; ll[j] = *(ushort*)&bl;
        }
        ((ushort4*)xh)[i] = make_ushort4(hh[0], hh[1], hh[2], hh[3]);
        ((ushort4*)xl)[i] = make_ushort4(ll[0], ll[1], ll[2], ll[3]);
    } else if (bid < 4352) {
        // ---- convert_w: W1[k][n] -> wth[n][k], wtl[n][k] (transposed split bf16) ----
        int t = (bid - 4096) * 256 + threadIdx.x;
        int n  = t & (DD - 1);
        int kq = t >> 9;
        ushort hh[4], ll[4];
        #pragma unroll
        for (int i = 0; i < 4; ++i) {
            float f = W1[(size_t)(kq * 4 + i) * DD + n];
            __hip_bfloat16 bh = __float2bfloat16(f);
            float r = f - __bfloat162float(bh);
            __hip_bfloat16 bl = __float2bfloat16(r);
            hh[i] = *(ushort*)&bh; ll[i] = *(ushort*)&bl;
        }
        ((ushort4*)wth)[(size_t)n * (DD / 4) + kq] = make_ushort4(hh[0], hh[1], hh[2], hh[3]);
        ((ushort4*)wtl)[(size_t)n * (DD / 4) + kq] = make_ushort4(ll[0], ll[1], ll[2], ll[3]);
    } else {
        // ---- cumsum: 256 threads scan 512 entries (Hillis-Steele, 2 elems/thread) ----
        int b = bid - 4352;
        __shared__ int s[TT];
        int t = threadIdx.x;
        s[t]       = target[b * TT + t];
        s[t + 256] = target[b * TT + t + 256];
        __syncthreads();
        #pragma unroll
        for (int off = 1; off < TT; off <<= 1) {
            int v0 = (t >= off) ? s[t - off] : 0;
            int v1 = s[t + 256 - off];          // t+256 >= 256 >= off always
            __syncthreads();
            s[t] += v0;
            s[t + 256] += v1;
            __syncthreads();
        }
        cs[b * TT + t]       = s[t];
        cs[b * TT + t + 256] = s[t + 256];
    }
}

// ================= mega: bf16x3 MFMA GEMM blocks + length-regulate blocks =================
// bid < NGEMM: gemm role (tile 128x128, BK=32, double-buffered, swizzled LDS).
// bid >= NGEMM: lr role (gather+pad 64 output rows, float4-coalesced).
// Fusion rationale: gemm is MFMA/LDS-bound with HBM idle; lr is pure HBM-write.
// Co-resident on each CU (64KB + 64KB LDS <= 160KB) they overlap: total ~ max, not sum.
#define BM 128
#define BN 128
#define BK 32
__global__ __launch_bounds__(256) void mega_kernel(const ushort* __restrict__ xh,
                                                   const ushort* __restrict__ xl,
                                                   const ushort* __restrict__ wth,
                                                   const ushort* __restrict__ wtl,
                                                   const float* __restrict__ b1,
                                                   const float* __restrict__ W2,
                                                   const float* __restrict__ x,
                                                   const int* __restrict__ cs,
                                                   float* __restrict__ out,
                                                   float* __restrict__ partial,
                                                   int L) {
    __shared__ ushort lds[2][2][128 * 64];   // 64 KB; lr role reuses first 2 KB
    const int bid = blockIdx.x;
    const int t = threadIdx.x;

    if (bid >= NGEMM) {
        // ---------------- lr role ----------------
        int bid2 = bid - NGEMM;
        int b = bid2 >> 6;
        int rowblk = bid2 & 63;
        int* scs = (int*)&lds[0][0][0];
        for (int i = t; i < TT; i += 256) scs[i] = cs[b * TT + i];
        __syncthreads();
        int total = scs[TT - 1];
        int group = t >> 7;
        int lane  = t & 127;
        int row0  = rowblk * 64;
        const float4* x4 = (const float4*)(x + (size_t)b * TT * DD);
        float4*       o4 = (float4*)(out + (size_t)b * L * DD);
        for (int r = row0 + group; r < row0 + 64; r += 2) {
            int l = r;
            float4 v = make_float4(0.f, 0.f, 0.f, 0.f);
            if (l < total) {
                int lo = 0, hi = TT;
                while (lo < hi) {
                    int mid = (lo + hi) >> 1;
                    if (scs[mid] <= l) lo = mid + 1; else hi = mid;
                }
                int idx = lo < (TT - 1) ? lo : (TT - 1);
                v = x4[idx * (DD / 4) + lane];
            }
            o4[(size_t)l * (DD / 4) + lane] = v;
        }
        return;
    }

    // ---------------- gemm role ----------------
    const int lane = t & 63, wave = t >> 6;
    const int row0 = (bid >> 2) * BM;
    const int col0 = (bid & 3) * BN;
    const int rq = t >> 3;                   // row within a 32-row issue chunk
    const int ls = (t & 7) ^ (rq & 7);       // logical slot this lane must FETCH
    const int sco = (ls & 3) * 8;            // k-subcolumn within tile

    auto stage = [&](int buf, int kt) {
        const int k0 = kt * BK;
        const ushort* srcA = (ls < 4) ? xh : xl;
        const ushort* srcB = (ls < 4) ? wth : wtl;
        #pragma unroll
        for (int q = 0; q < 4; ++q) {
            int row = q * 32 + rq;
            const ushort* ga = srcA + (size_t)(row0 + row) * DD + k0 + sco;
            auto la = (__attribute__((address_space(3))) unsigned int*)
                      ((char*)&lds[buf][0][0] + q * 4096 + wave * 1024);
            __builtin_amdgcn_global_load_lds(
                (const __attribute__((address_space(1))) unsigned int*)ga, la, 16, 0, 0);
        }
        #pragma unroll
        for (int q = 0; q < 4; ++q) {
            int row = q * 32 + rq;
            const ushort* gb = srcB + (size_t)(col0 + row) * DD + k0 + sco;
            auto lb = (__attribute__((address_space(3))) unsigned int*)
                      ((char*)&lds[buf][1][0] + q * 4096 + wave * 1024);
            __builtin_amdgcn_global_load_lds(
                (const __attribute__((address_space(1))) unsigned int*)gb, lb, 16, 0, 0);
        }
    };

    const int wm = (wave >> 1) * 64;
    const int wn = (wave & 1) * 64;
    const int l15 = lane & 15, l4 = lane >> 4;
    f32x4 acc[4][4] = {};

    stage(0, 0);
    __syncthreads();
    int cur = 0;
    #pragma unroll 1
    for (int kt = 0; kt < DD / BK; ++kt) {
        if (kt + 1 < DD / BK) stage(cur ^ 1, kt + 1);
        const ushort* At = &lds[cur][0][0];
        const ushort* Bt = &lds[cur][1][0];
        bf16x8 ah[4], al[4], bh[4], bl[4];
        #pragma unroll
        for (int i = 0; i < 4; ++i) {
            int r = wm + i * 16 + l15;
            int s0 = l4 ^ (r & 7);
            int s1 = (4 + l4) ^ (r & 7);
            ah[i] = *(const bf16x8*)&At[r * 64 + s0 * 8];
            al[i] = *(const bf16x8*)&At[r * 64 + s1 * 8];
        }
        #pragma unroll
        for (int j = 0; j < 4; ++j) {
            int r = wn + j * 16 + l15;
            int s0 = l4 ^ (r & 7);
            int s1 = (4 + l4) ^ (r & 7);
            bh[j] = *(const bf16x8*)&Bt[r * 64 + s0 * 8];
            bl[j] = *(const bf16x8*)&Bt[r * 64 + s1 * 8];
        }
        #pragma unroll
        for (int i = 0; i < 4; ++i)
            #pragma unroll
            for (int j = 0; j < 4; ++j) {
                acc[i][j] = __builtin_amdgcn_mfma_f32_16x16x32_bf16(ah[i], bh[j], acc[i][j], 0, 0, 0);
                acc[i][j] = __builtin_amdgcn_mfma_f32_16x16x32_bf16(ah[i], bl[j], acc[i][j], 0, 0, 0);
                acc[i][j] = __builtin_amdgcn_mfma_f32_16x16x32_bf16(al[i], bh[j], acc[i][j], 0, 0, 0);
            }
        __syncthreads();
        cur ^= 1;
    }

    // epilogue: relu(acc + b1) dot W2; partial slice = col-block*2 + col-half
    const int pslice = (bid & 3) * 2 + (wn >> 6);
    #pragma unroll
    for (int i = 0; i < 4; ++i) {
        #pragma unroll
        for (int r = 0; r < 4; ++r) {
            float s = 0.f;
            #pragma unroll
            for (int j = 0; j < 4; ++j) {
                int cg = col0 + wn + j * 16 + l15;
                float h = acc[i][j][r] + b1[cg];
                h = fmaxf(h, 0.f);
                s += h * W2[cg];
            }
            s += __shfl_xor(s, 1);
            s += __shfl_xor(s, 2);
            s += __shfl_xor(s, 4);
            s += __shfl_xor(s, 8);
            if (l15 == 0) {
                int rg = row0 + wm + i * 16 + l4 * 4 + r;
                partial[(size_t)pslice * MM + rg] = s;
            }
        }
    }
}

// ---------------- final dpo: relu(sum of 8 partials + b2) ----------------
__global__ __launch_bounds__(256) void dpo_kernel(const float* __restrict__ partial,
                                                  const float* __restrict__ b2,
                                                  float* __restrict__ dpo) {
    int m = blockIdx.x * 256 + threadIdx.x;
    float s = b2[0];
    #pragma unroll
    for (int nb = 0; nb < NPART; ++nb) s += partial[(size_t)nb * MM + m];
    dpo[m] = fmaxf(s, 0.f);
}

extern "C" void kernel_launch(void* const* d_in, const int* in_sizes, int n_in,
                              void* d_out, int out_size, void* d_ws, size_t ws_size,
                              hipStream_t stream) {
    const float* x      = (const float*)d_in[0];
    const float* W1     = (const float*)d_in[1];
    const float* b1     = (const float*)d_in[2];
    const float* W2     = (const float*)d_in[3];
    const float* b2     = (const float*)d_in[4];
    const int*   target = (const int*)d_in[5];
    int L = (out_size - BSZ * TT) / (BSZ * DD);   // = 4096

    float* out_lr  = (float*)d_out;                        // [B, L, D]
    float* out_dpo = (float*)d_out + (size_t)BSZ * L * DD; // [B, T]

    // ws layout
    ushort* xh      = (ushort*)d_ws;                        // 8 MiB
    ushort* xl      = xh + (size_t)MM * DD;                 // 8 MiB
    ushort* wth     = xl + (size_t)MM * DD;                 // 512 KiB
    ushort* wtl     = wth + (size_t)DD * DD;                // 512 KiB
    float*  partial = (float*)(wtl + (size_t)DD * DD);      // 8*8192 floats
    int*    cs      = (int*)(partial + (size_t)NPART * MM); // 16*512 ints

    prep_kernel<<<dim3(4368), dim3(256), 0, stream>>>(x, W1, target, xh, xl, wth, wtl, cs);
    mega_kernel<<<dim3(NGEMM + NLR), dim3(256), 0, stream>>>(xh, xl, wth, wtl, b1, W2,
                                                             x, cs, out_lr, partial, L);
    dpo_kernel<<<dim3(MM / 256), dim3(256), 0, stream>>>(partial, b2, out_dpo);
}

// Round 5
// 58.589 us; speedup vs baseline: 1.3171x; 1.3171x over previous
//
#include <hip/hip_runtime.h>
#include <hip/hip_bf16.h>

#define BSZ 16
#define TT 512
#define DD 512
#define MM (BSZ * TT)          // 8192 rows for the GEMM
#define NCB 4                  // N=512 / BN=128 col-blocks
#define NPART (NCB * 2)        // partial slices: col-block x col-half
#define NGEMM 256              // gemm blocks; each also owns 256 LR frames

typedef __attribute__((ext_vector_type(8))) short bf16x8;
typedef __attribute__((ext_vector_type(4))) float f32x4;

// ================= prep: convert_x + convert_w + cumsum->imap in one launch =================
// grid: [0,4096) convert_x | [4096,4352) convert_w | [4352,4368) cumsum+imap scatter
__global__ __launch_bounds__(256) void prep_kernel(const float* __restrict__ x,
                                                   const float* __restrict__ W1,
                                                   const int* __restrict__ target,
                                                   ushort* __restrict__ xh,
                                                   ushort* __restrict__ xl,
                                                   ushort* __restrict__ wth,
                                                   ushort* __restrict__ wtl,
                                                   int* __restrict__ imap, int L) {
    int bid = blockIdx.x;
    if (bid < 4096) {
        // ---- convert_x: x -> xh + xl (split bf16), 4 floats/thread ----
        int i = bid * 256 + threadIdx.x;
        float4 v = ((const float4*)x)[i];
        float f[4] = {v.x, v.y, v.z, v.w};
        ushort hh[4], ll[4];
        #pragma unroll
        for (int j = 0; j < 4; ++j) {
            __hip_bfloat16 bh = __float2bfloat16(f[j]);
            float r = f[j] - __bfloat162float(bh);
            __hip_bfloat16 bl = __float2bfloat16(r);
            hh[j] = *(ushort*)&bh; ll[j] = *(ushort*)&bl;
        }
        ((ushort4*)xh)[i] = make_ushort4(hh[0], hh[1], hh[2], hh[3]);
        ((ushort4*)xl)[i] = make_ushort4(ll[0], ll[1], ll[2], ll[3]);
    } else if (bid < 4352) {
        // ---- convert_w: W1[k][n] -> wth[n][k], wtl[n][k] (transposed split bf16) ----
        int t = (bid - 4096) * 256 + threadIdx.x;
        int n  = t & (DD - 1);
        int kq = t >> 9;
        ushort hh[4], ll[4];
        #pragma unroll
        for (int i = 0; i < 4; ++i) {
            float f = W1[(size_t)(kq * 4 + i) * DD + n];
            __hip_bfloat16 bh = __float2bfloat16(f);
            float r = f - __bfloat162float(bh);
            __hip_bfloat16 bl = __float2bfloat16(r);
            hh[i] = *(ushort*)&bh; ll[i] = *(ushort*)&bl;
        }
        ((ushort4*)wth)[(size_t)n * (DD / 4) + kq] = make_ushort4(hh[0], hh[1], hh[2], hh[3]);
        ((ushort4*)wtl)[(size_t)n * (DD / 4) + kq] = make_ushort4(ll[0], ll[1], ll[2], ll[3]);
    } else {
        // ---- cumsum (256 thr x 2 elems) then scatter frame->phoneme index map ----
        int b = bid - 4352;
        __shared__ int s[TT];
        int t = threadIdx.x;
        s[t]       = target[b * TT + t];
        s[t + 256] = target[b * TT + t + 256];
        __syncthreads();
        #pragma unroll
        for (int off = 1; off < TT; off <<= 1) {
            int v0 = (t >= off) ? s[t - off] : 0;
            int v1 = s[t + 256 - off];
            __syncthreads();
            s[t] += v0;
            s[t + 256] += v1;
            __syncthreads();
        }
        int total = s[TT - 1];
        int* imb = imap + (size_t)b * L;
        // scatter: frames [cs[ph-1], cs[ph]) -> ph   (searchsorted side='right')
        for (int ph = t; ph < TT; ph += 256) {
            int st = (ph == 0) ? 0 : s[ph - 1];
            int en = s[ph];
            for (int d = st; d < en; ++d) imb[d] = ph;
        }
        // pad region -> -1 (disjoint from scatter range)
        for (int l = total + t; l < L; l += 256) imb[l] = -1;
    }
}

// ================= mega: bf16x3 MFMA GEMM with LR stores interleaved per K-step =========
// 256 blocks. Block bid: gemm tile (row0=(bid>>2)*128, col0=(bid&3)*128) AND 256 LR
// frames of the SAME batch (b = bid>>4, frames [(bid&15)*256, +256)). Per K-step:
// issue 8 idx loads + 8 gathered float4 reads (latency hides under ds_read+MFMA),
// store 8 float4 after MFMA; stores retire to L2 at the barrier drain while HBM
// drains asynchronously -> LR write BW overlaps MFMA: total ~ max, not sum.
#define BM 128
#define BN 128
#define BK 32
__global__ __launch_bounds__(256) void mega_kernel(const ushort* __restrict__ xh,
                                                   const ushort* __restrict__ xl,
                                                   const ushort* __restrict__ wth,
                                                   const ushort* __restrict__ wtl,
                                                   const float* __restrict__ b1,
                                                   const float* __restrict__ W2,
                                                   const float* __restrict__ x,
                                                   const int* __restrict__ imap,
                                                   float* __restrict__ out,
                                                   float* __restrict__ partial,
                                                   int L) {
    __shared__ ushort lds[2][2][128 * 64];   // 64 KB double-buffered A/B tiles
    const int bid = blockIdx.x;
    const int t = threadIdx.x;
    const int lane = t & 63, wave = t >> 6;
    const int row0 = (bid >> 2) * BM;
    const int col0 = (bid & 3) * BN;
    const int rq = t >> 3;                   // row within a 32-row issue chunk
    const int ls = (t & 7) ^ (rq & 7);       // logical slot this lane must FETCH
    const int sco = (ls & 3) * 8;            // k-subcolumn within tile

    // LR assignment: same batch as this tile's A-rows (L2 locality)
    const int b_lr   = bid >> 4;
    const int chunk0 = (bid & 15) * 256;
    const int lr_lane = t & 127;             // float4 index within a 512-float row
    const int lr_half = t >> 7;              // 0/1: which of the 2 rows per pass
    const float4* x4g = (const float4*)(x + (size_t)b_lr * TT * DD);
    float4*       o4  = (float4*)(out + (size_t)b_lr * L * DD);
    const int*    imb = imap + (size_t)b_lr * L;

    auto stage = [&](int buf, int kt) {
        const int k0 = kt * BK;
        const ushort* srcA = (ls < 4) ? xh : xl;
        const ushort* srcB = (ls < 4) ? wth : wtl;
        #pragma unroll
        for (int q = 0; q < 4; ++q) {
            int row = q * 32 + rq;
            const ushort* ga = srcA + (size_t)(row0 + row) * DD + k0 + sco;
            auto la = (__attribute__((address_space(3))) unsigned int*)
                      ((char*)&lds[buf][0][0] + q * 4096 + wave * 1024);
            __builtin_amdgcn_global_load_lds(
                (const __attribute__((address_space(1))) unsigned int*)ga, la, 16, 0, 0);
        }
        #pragma unroll
        for (int q = 0; q < 4; ++q) {
            int row = q * 32 + rq;
            const ushort* gb = srcB + (size_t)(col0 + row) * DD + k0 + sco;
            auto lb = (__attribute__((address_space(3))) unsigned int*)
                      ((char*)&lds[buf][1][0] + q * 4096 + wave * 1024);
            __builtin_amdgcn_global_load_lds(
                (const __attribute__((address_space(1))) unsigned int*)gb, lb, 16, 0, 0);
        }
    };

    const int wm = (wave >> 1) * 64;
    const int wn = (wave & 1) * 64;
    const int l15 = lane & 15, l4 = lane >> 4;
    f32x4 acc[4][4] = {};

    stage(0, 0);
    __syncthreads();
    int cur = 0;
    #pragma unroll 1
    for (int kt = 0; kt < DD / BK; ++kt) {
        if (kt + 1 < DD / BK) stage(cur ^ 1, kt + 1);

        // ---- LR phase 1: issue idx loads + gathers for this step's 16 rows ----
        const int rbase = chunk0 + kt * 16 + lr_half;
        int idxs[8];
        #pragma unroll
        for (int p = 0; p < 8; ++p) idxs[p] = imb[rbase + p * 2];
        float4 gv[8];
        #pragma unroll
        for (int p = 0; p < 8; ++p)
            gv[p] = (idxs[p] >= 0) ? x4g[(size_t)idxs[p] * (DD / 4) + lr_lane]
                                   : make_float4(0.f, 0.f, 0.f, 0.f);

        const ushort* At = &lds[cur][0][0];
        const ushort* Bt = &lds[cur][1][0];
        bf16x8 ah[4], al[4], bh[4], bl[4];
        #pragma unroll
        for (int i = 0; i < 4; ++i) {
            int r = wm + i * 16 + l15;
            int s0 = l4 ^ (r & 7);
            int s1 = (4 + l4) ^ (r & 7);
            ah[i] = *(const bf16x8*)&At[r * 64 + s0 * 8];
            al[i] = *(const bf16x8*)&At[r * 64 + s1 * 8];
        }
        #pragma unroll
        for (int j = 0; j < 4; ++j) {
            int r = wn + j * 16 + l15;
            int s0 = l4 ^ (r & 7);
            int s1 = (4 + l4) ^ (r & 7);
            bh[j] = *(const bf16x8*)&Bt[r * 64 + s0 * 8];
            bl[j] = *(const bf16x8*)&Bt[r * 64 + s1 * 8];
        }
        #pragma unroll
        for (int i = 0; i < 4; ++i)
            #pragma unroll
            for (int j = 0; j < 4; ++j) {
                acc[i][j] = __builtin_amdgcn_mfma_f32_16x16x32_bf16(ah[i], bh[j], acc[i][j], 0, 0, 0);
                acc[i][j] = __builtin_amdgcn_mfma_f32_16x16x32_bf16(ah[i], bl[j], acc[i][j], 0, 0, 0);
                acc[i][j] = __builtin_amdgcn_mfma_f32_16x16x32_bf16(al[i], bh[j], acc[i][j], 0, 0, 0);
            }

        // ---- LR phase 2: store the 16 rows (stores retire to L2 at barrier drain) ----
        #pragma unroll
        for (int p = 0; p < 8; ++p)
            o4[(size_t)(rbase + p * 2) * (DD / 4) + lr_lane] = gv[p];

        __syncthreads();
        cur ^= 1;
    }

    // epilogue: relu(acc + b1) dot W2; partial slice = col-block*2 + col-half
    const int pslice = (bid & 3) * 2 + (wn >> 6);
    #pragma unroll
    for (int i = 0; i < 4; ++i) {
        #pragma unroll
        for (int r = 0; r < 4; ++r) {
            float s = 0.f;
            #pragma unroll
            for (int j = 0; j < 4; ++j) {
                int cg = col0 + wn + j * 16 + l15;
                float h = acc[i][j][r] + b1[cg];
                h = fmaxf(h, 0.f);
                s += h * W2[cg];
            }
            s += __shfl_xor(s, 1);
            s += __shfl_xor(s, 2);
            s += __shfl_xor(s, 4);
            s += __shfl_xor(s, 8);
            if (l15 == 0) {
                int rg = row0 + wm + i * 16 + l4 * 4 + r;
                partial[(size_t)pslice * MM + rg] = s;
            }
        }
    }
}

// ---------------- final dpo: relu(sum of 8 partials + b2) ----------------
__global__ __launch_bounds__(256) void dpo_kernel(const float* __restrict__ partial,
                                                  const float* __restrict__ b2,
                                                  float* __restrict__ dpo) {
    int m = blockIdx.x * 256 + threadIdx.x;
    float s = b2[0];
    #pragma unroll
    for (int nb = 0; nb < NPART; ++nb) s += partial[(size_t)nb * MM + m];
    dpo[m] = fmaxf(s, 0.f);
}

extern "C" void kernel_launch(void* const* d_in, const int* in_sizes, int n_in,
                              void* d_out, int out_size, void* d_ws, size_t ws_size,
                              hipStream_t stream) {
    const float* x      = (const float*)d_in[0];
    const float* W1     = (const float*)d_in[1];
    const float* b1     = (const float*)d_in[2];
    const float* W2     = (const float*)d_in[3];
    const float* b2     = (const float*)d_in[4];
    const int*   target = (const int*)d_in[5];
    int L = (out_size - BSZ * TT) / (BSZ * DD);   // = 4096

    float* out_lr  = (float*)d_out;                        // [B, L, D]
    float* out_dpo = (float*)d_out + (size_t)BSZ * L * DD; // [B, T]

    // ws layout
    ushort* xh      = (ushort*)d_ws;                        // 8 MiB
    ushort* xl      = xh + (size_t)MM * DD;                 // 8 MiB
    ushort* wth     = xl + (size_t)MM * DD;                 // 512 KiB
    ushort* wtl     = wth + (size_t)DD * DD;                // 512 KiB
    float*  partial = (float*)(wtl + (size_t)DD * DD);      // 8*8192 floats
    int*    imap    = (int*)(partial + (size_t)NPART * MM); // 16*4096 ints

    prep_kernel<<<dim3(4368), dim3(256), 0, stream>>>(x, W1, target, xh, xl, wth, wtl, imap, L);
    mega_kernel<<<dim3(NGEMM), dim3(256), 0, stream>>>(xh, xl, wth, wtl, b1, W2,
                                                       x, imap, out_lr, partial, L);
    dpo_kernel<<<dim3(MM / 256), dim3(256), 0, stream>>>(partial, b2, out_dpo);
}

// Round 6
// 44.442 us; speedup vs baseline: 1.7364x; 1.3183x over previous
//
#include <hip/hip_runtime.h>
#include <hip/hip_bf16.h>

#define BSZ 16
#define TT 512
#define DD 512
#define MM (BSZ * TT)          // 8192 rows for the GEMM
#define NCB 4                  // N=512 / BN=128 col-blocks
#define NPART (NCB * 2)        // partial slices: col-block x col-half
#define NGEMM 256              // gemm blocks; each also owns 256 LR frames

typedef __attribute__((ext_vector_type(8))) short bf16x8;
typedef __attribute__((ext_vector_type(4))) float f32x4;

// ================= prep: convert_x + convert_w + cumsum->imap in one launch =================
// grid: [0,4096) convert_x | [4096,4352) convert_w | [4352,4368) cumsum+imap scatter
__global__ __launch_bounds__(256) void prep_kernel(const float* __restrict__ x,
                                                   const float* __restrict__ W1,
                                                   const int* __restrict__ target,
                                                   ushort* __restrict__ xh,
                                                   ushort* __restrict__ wth,
                                                   int* __restrict__ imap, int L) {
    int bid = blockIdx.x;
    if (bid < 4096) {
        // ---- convert_x: x -> bf16 (round-to-nearest via __float2bfloat16) ----
        int i = bid * 256 + threadIdx.x;
        float4 v = ((const float4*)x)[i];
        float f[4] = {v.x, v.y, v.z, v.w};
        ushort hh[4];
        #pragma unroll
        for (int j = 0; j < 4; ++j) {
            __hip_bfloat16 bh = __float2bfloat16(f[j]);
            hh[j] = *(ushort*)&bh;
        }
        ((ushort4*)xh)[i] = make_ushort4(hh[0], hh[1], hh[2], hh[3]);
    } else if (bid < 4352) {
        // ---- convert_w: W1[k][n] -> wth[n][k] (transposed bf16) ----
        int t = (bid - 4096) * 256 + threadIdx.x;
        int n  = t & (DD - 1);
        int kq = t >> 9;
        ushort hh[4];
        #pragma unroll
        for (int i = 0; i < 4; ++i) {
            float f = W1[(size_t)(kq * 4 + i) * DD + n];
            __hip_bfloat16 bh = __float2bfloat16(f);
            hh[i] = *(ushort*)&bh;
        }
        ((ushort4*)wth)[(size_t)n * (DD / 4) + kq] = make_ushort4(hh[0], hh[1], hh[2], hh[3]);
    } else {
        // ---- cumsum (256 thr x 2 elems) then scatter frame->phoneme index map ----
        int b = bid - 4352;
        __shared__ int s[TT];
        int t = threadIdx.x;
        s[t]       = target[b * TT + t];
        s[t + 256] = target[b * TT + t + 256];
        __syncthreads();
        #pragma unroll
        for (int off = 1; off < TT; off <<= 1) {
            int v0 = (t >= off) ? s[t - off] : 0;
            int v1 = s[t + 256 - off];
            __syncthreads();
            s[t] += v0;
            s[t + 256] += v1;
            __syncthreads();
        }
        int total = s[TT - 1];
        int* imb = imap + (size_t)b * L;
        for (int ph = t; ph < TT; ph += 256) {
            int st = (ph == 0) ? 0 : s[ph - 1];
            int en = s[ph];
            for (int d = st; d < en; ++d) imb[d] = ph;
        }
        for (int l = total + t; l < L; l += 256) imb[l] = -1;
    }
}

// ================= mega: bf16 MFMA GEMM (BK=64) with LR interleaved per K-step =========
// 256 blocks. Block bid: gemm tile (row0=(bid>>2)*128, col0=(bid&3)*128) AND 256 LR
// frames of batch bid>>4. 8 K-steps; per step 32 LR frames in two 16-row passes that
// straddle the two MFMA half-clusters (gather latency hides under ds_read/MFMA;
// stores drain to L2 at the barrier while HBM drains async under the next step).
// LDS row = 128 B (64 ushorts, 8 slots of 16 B), XOR swizzle slot ^= (row&7);
// global_load_lds writes linearly so the global SOURCE k-offset is pre-inverse-swizzled.
#define BM 128
#define BN 128
#define BK 64
__global__ __launch_bounds__(256) void mega_kernel(const ushort* __restrict__ xh,
                                                   const ushort* __restrict__ wth,
                                                   const float* __restrict__ b1,
                                                   const float* __restrict__ W2,
                                                   const float* __restrict__ x,
                                                   const int* __restrict__ imap,
                                                   float* __restrict__ out,
                                                   float* __restrict__ partial,
                                                   int L) {
    __shared__ ushort lds[2][2][128 * 64];   // [buf][A/B][row*64 + slot*8 + e] = 64 KB
    const int bid = blockIdx.x;
    const int t = threadIdx.x;
    const int lane = t & 63, wave = t >> 6;
    const int row0 = (bid >> 2) * BM;
    const int col0 = (bid & 3) * BN;
    const int rq = t >> 3;                   // row within a 32-row issue chunk
    const int ls = (t & 7) ^ (rq & 7);       // logical slot this lane must FETCH
    const int sco = ls * 8;                  // k-subcolumn (ushorts) within tile

    // LR assignment: same batch as this tile's A-rows (L2 locality)
    const int b_lr    = bid >> 4;
    const int chunk0  = (bid & 15) * 256;
    const int lr_lane = t & 127;             // float4 index within a 512-float row
    const int lr_half = t >> 7;              // 0/1
    const float4* x4g = (const float4*)(x + (size_t)b_lr * TT * DD);
    float4*       o4  = (float4*)(out + (size_t)b_lr * L * DD);
    const int*    imb = imap + (size_t)b_lr * L;

    auto stage = [&](int buf, int kt) {
        const int k0 = kt * BK;
        #pragma unroll
        for (int q = 0; q < 4; ++q) {
            int row = q * 32 + rq;
            const ushort* ga = xh + (size_t)(row0 + row) * DD + k0 + sco;
            auto la = (__attribute__((address_space(3))) unsigned int*)
                      ((char*)&lds[buf][0][0] + q * 4096 + wave * 1024);
            __builtin_amdgcn_global_load_lds(
                (const __attribute__((address_space(1))) unsigned int*)ga, la, 16, 0, 0);
        }
        #pragma unroll
        for (int q = 0; q < 4; ++q) {
            int row = q * 32 + rq;
            const ushort* gb = wth + (size_t)(col0 + row) * DD + k0 + sco;
            auto lb = (__attribute__((address_space(3))) unsigned int*)
                      ((char*)&lds[buf][1][0] + q * 4096 + wave * 1024);
            __builtin_amdgcn_global_load_lds(
                (const __attribute__((address_space(1))) unsigned int*)gb, lb, 16, 0, 0);
        }
    };

    const int wm = (wave >> 1) * 64;
    const int wn = (wave & 1) * 64;
    const int l15 = lane & 15, l4 = lane >> 4;
    f32x4 acc[4][4] = {};

    stage(0, 0);
    __syncthreads();
    int cur = 0;
    #pragma unroll 1
    for (int kt = 0; kt < DD / BK; ++kt) {
        if (kt + 1 < DD / BK) stage(cur ^ 1, kt + 1);

        // ---- LR pass 0: gather 16 rows ----
        const int rb0 = chunk0 + kt * 32 + lr_half;
        int idx0[8];
        #pragma unroll
        for (int p = 0; p < 8; ++p) idx0[p] = imb[rb0 + p * 2];
        float4 gv[8];
        #pragma unroll
        for (int p = 0; p < 8; ++p)
            gv[p] = (idx0[p] >= 0) ? x4g[(size_t)idx0[p] * (DD / 4) + lr_lane]
                                   : make_float4(0.f, 0.f, 0.f, 0.f);

        const ushort* At = &lds[cur][0][0];
        const ushort* Bt = &lds[cur][1][0];
        bf16x8 a[4][2], b[4][2];
        #pragma unroll
        for (int i = 0; i < 4; ++i) {
            int r = wm + i * 16 + l15;
            #pragma unroll
            for (int ks = 0; ks < 2; ++ks) {
                int sl = (ks * 4 + l4) ^ (r & 7);
                a[i][ks] = *(const bf16x8*)&At[r * 64 + sl * 8];
            }
        }
        #pragma unroll
        for (int j = 0; j < 4; ++j) {
            int r = wn + j * 16 + l15;
            #pragma unroll
            for (int ks = 0; ks < 2; ++ks) {
                int sl = (ks * 4 + l4) ^ (r & 7);
                b[j][ks] = *(const bf16x8*)&Bt[r * 64 + sl * 8];
            }
        }

        // ---- MFMA half-cluster ks=0 ----
        #pragma unroll
        for (int i = 0; i < 4; ++i)
            #pragma unroll
            for (int j = 0; j < 4; ++j)
                acc[i][j] = __builtin_amdgcn_mfma_f32_16x16x32_bf16(a[i][0], b[j][0], acc[i][j], 0, 0, 0);

        // ---- LR pass 0 store + pass 1 gather ----
        #pragma unroll
        for (int p = 0; p < 8; ++p)
            o4[(size_t)(rb0 + p * 2) * (DD / 4) + lr_lane] = gv[p];
        const int rb1 = rb0 + 16;
        int idx1[8];
        #pragma unroll
        for (int p = 0; p < 8; ++p) idx1[p] = imb[rb1 + p * 2];
        #pragma unroll
        for (int p = 0; p < 8; ++p)
            gv[p] = (idx1[p] >= 0) ? x4g[(size_t)idx1[p] * (DD / 4) + lr_lane]
                                   : make_float4(0.f, 0.f, 0.f, 0.f);

        // ---- MFMA half-cluster ks=1 ----
        #pragma unroll
        for (int i = 0; i < 4; ++i)
            #pragma unroll
            for (int j = 0; j < 4; ++j)
                acc[i][j] = __builtin_amdgcn_mfma_f32_16x16x32_bf16(a[i][1], b[j][1], acc[i][j], 0, 0, 0);

        // ---- LR pass 1 store ----
        #pragma unroll
        for (int p = 0; p < 8; ++p)
            o4[(size_t)(rb1 + p * 2) * (DD / 4) + lr_lane] = gv[p];

        __syncthreads();
        cur ^= 1;
    }

    // epilogue: relu(acc + b1) dot W2; partial slice = col-block*2 + col-half
    const int pslice = (bid & 3) * 2 + (wn >> 6);
    #pragma unroll
    for (int i = 0; i < 4; ++i) {
        #pragma unroll
        for (int r = 0; r < 4; ++r) {
            float s = 0.f;
            #pragma unroll
            for (int j = 0; j < 4; ++j) {
                int cg = col0 + wn + j * 16 + l15;
                float h = acc[i][j][r] + b1[cg];
                h = fmaxf(h, 0.f);
                s += h * W2[cg];
            }
            s += __shfl_xor(s, 1);
            s += __shfl_xor(s, 2);
            s += __shfl_xor(s, 4);
            s += __shfl_xor(s, 8);
            if (l15 == 0) {
                int rg = row0 + wm + i * 16 + l4 * 4 + r;
                partial[(size_t)pslice * MM + rg] = s;
            }
        }
    }
}

// ---------------- final dpo: relu(sum of 8 partials + b2) ----------------
__global__ __launch_bounds__(256) void dpo_kernel(const float* __restrict__ partial,
                                                  const float* __restrict__ b2,
                                                  float* __restrict__ dpo) {
    int m = blockIdx.x * 256 + threadIdx.x;
    float s = b2[0];
    #pragma unroll
    for (int nb = 0; nb < NPART; ++nb) s += partial[(size_t)nb * MM + m];
    dpo[m] = fmaxf(s, 0.f);
}

extern "C" void kernel_launch(void* const* d_in, const int* in_sizes, int n_in,
                              void* d_out, int out_size, void* d_ws, size_t ws_size,
                              hipStream_t stream) {
    const float* x      = (const float*)d_in[0];
    const float* W1     = (const float*)d_in[1];
    const float* b1     = (const float*)d_in[2];
    const float* W2     = (const float*)d_in[3];
    const float* b2     = (const float*)d_in[4];
    const int*   target = (const int*)d_in[5];
    int L = (out_size - BSZ * TT) / (BSZ * DD);   // = 4096

    float* out_lr  = (float*)d_out;                        // [B, L, D]
    float* out_dpo = (float*)d_out + (size_t)BSZ * L * DD; // [B, T]

    // ws layout
    ushort* xh      = (ushort*)d_ws;                        // 8 MiB
    ushort* wth     = xh + (size_t)MM * DD;                 // 512 KiB
    float*  partial = (float*)(wth + (size_t)DD * DD);      // 8*8192 floats
    int*    imap    = (int*)(partial + (size_t)NPART * MM); // 16*4096 ints

    prep_kernel<<<dim3(4368), dim3(256), 0, stream>>>(x, W1, target, xh, wth, imap, L);
    mega_kernel<<<dim3(NGEMM), dim3(256), 0, stream>>>(xh, wth, b1, W2,
                                                       x, imap, out_lr, partial, L);
    dpo_kernel<<<dim3(MM / 256), dim3(256), 0, stream>>>(partial, b2, out_dpo);
}

// Round 8
// 43.035 us; speedup vs baseline: 1.7932x; 1.0327x over previous
//
#include <hip/hip_runtime.h>
#include <hip/hip_bf16.h>

#define BSZ 16
#define TT 512
#define DD 512
#define MM (BSZ * TT)          // 8192 rows for the GEMM
#define NPART 8                // partial slices: 4 col-blocks x 2 col-halves
#define NMEGA 512              // mega blocks: 128 row-tiles x 4 col-tiles

typedef __attribute__((ext_vector_type(8))) short bf16x8;
typedef __attribute__((ext_vector_type(8))) unsigned short ushort8;
typedef __attribute__((ext_vector_type(4))) float f32x4;

// ================= prep: convert_w + cumsum->imap (272 blocks, ~1-2 us) =================
// grid: [0,256) convert_w | [256,272) cumsum+imap scatter
__global__ __launch_bounds__(256) void prep_kernel(const float* __restrict__ W1,
                                                   const int* __restrict__ target,
                                                   ushort* __restrict__ wth,
                                                   int* __restrict__ imap, int L) {
    int bid = blockIdx.x;
    if (bid < 256) {
        // ---- convert_w: W1[k][n] -> wth[n][k] (transposed bf16) ----
        int t = bid * 256 + threadIdx.x;
        int n  = t & (DD - 1);
        int kq = t >> 9;
        ushort hh[4];
        #pragma unroll
        for (int i = 0; i < 4; ++i) {
            float f = W1[(size_t)(kq * 4 + i) * DD + n];
            __hip_bfloat16 bh = __float2bfloat16(f);
            hh[i] = *(ushort*)&bh;
        }
        ((ushort4*)wth)[(size_t)n * (DD / 4) + kq] = make_ushort4(hh[0], hh[1], hh[2], hh[3]);
    } else {
        // ---- cumsum (256 thr x 2 elems) then scatter frame->phoneme index map ----
        int b = bid - 256;
        __shared__ int s[TT];
        int t = threadIdx.x;
        s[t]       = target[b * TT + t];
        s[t + 256] = target[b * TT + t + 256];
        __syncthreads();
        #pragma unroll
        for (int off = 1; off < TT; off <<= 1) {
            int v0 = (t >= off) ? s[t - off] : 0;
            int v1 = s[t + 256 - off];
            __syncthreads();
            s[t] += v0;
            s[t + 256] += v1;
            __syncthreads();
        }
        int total = s[TT - 1];
        int* imb = imap + (size_t)b * L;
        for (int ph = t; ph < TT; ph += 256) {
            int st = (ph == 0) ? 0 : s[ph - 1];
            int en = s[ph];
            for (int d = st; d < en; ++d) imb[d] = ph;
        }
        for (int l = total + t; l < L; l += 256) imb[l] = -1;
    }
}

// ================= mega: bf16 MFMA GEMM (64x128 tile, BK=64) + LR per K-step =========
// 512 blocks, 48 KB LDS -> 2 blocks/CU co-resident: one block's barrier drain hides
// under the other's MFMA/stores. A-tile reg-staged from fp32 x (load->cvt->swizzled
// ds_write; x is L3-resident); B-tile via global_load_lds with inverse-swizzled source.
// Block bid: tile (row0=(bid>>2)*64, col0=(bid&3)*128); LR frames: batch bid>>5,
// chunk (bid&31)*128, 16 frames per K-step (gather early, nontemporal store late).
#define BM 64
#define BN 128
#define BK 64
__global__ __launch_bounds__(256, 2) void mega_kernel(const ushort* __restrict__ wth,
                                                      const float* __restrict__ b1,
                                                      const float* __restrict__ W2,
                                                      const float* __restrict__ x,
                                                      const int* __restrict__ imap,
                                                      float* __restrict__ out,
                                                      float* __restrict__ partial,
                                                      int L) {
    __shared__ ushort ldsA[2][BM * 64];   // [buf][row*64 + slot*8 + e] = 2x8 KB
    __shared__ ushort ldsB[2][BN * 64];   // 2x16 KB; total 48 KB
    const int bid = blockIdx.x;
    const int t = threadIdx.x;
    const int lane = t & 63, wave = t >> 6;
    const int row0 = (bid >> 2) * BM;
    const int col0 = (bid & 3) * BN;
    const int rq = t >> 3;                   // 0..31: row within a 32-row B chunk
    const int ls = (t & 7) ^ (rq & 7);       // logical slot this lane must FETCH (B)
    const int sco = ls * 8;                  // k-subcolumn (ushorts)
    const int ar = t >> 2;                   // 0..63: A row this thread stages
    const int ac = (t & 3) * 16;             // 16-float k-chunk within A row

    // LR assignment: same batch as this tile's A-rows (L2 locality)
    const int b_lr    = bid >> 5;
    const int chunk0  = (bid & 31) * 128;
    const int lr_lane = t & 127;             // f32x4 index within a 512-float row
    const int lr_half = t >> 7;              // 0/1
    const f32x4* x4g = (const f32x4*)(x + (size_t)b_lr * TT * DD);
    f32x4*       o4  = (f32x4*)(out + (size_t)b_lr * L * DD);
    const int*   imb = imap + (size_t)b_lr * L;

    auto stageB = [&](int buf, int kt) {
        const int k0 = kt * BK;
        #pragma unroll
        for (int q = 0; q < 4; ++q) {
            int row = q * 32 + rq;
            const ushort* gb = wth + (size_t)(col0 + row) * DD + k0 + sco;
            auto lb = (__attribute__((address_space(3))) unsigned int*)
                      ((char*)&ldsB[buf][0] + q * 4096 + wave * 1024);
            __builtin_amdgcn_global_load_lds(
                (const __attribute__((address_space(1))) unsigned int*)gb, lb, 16, 0, 0);
        }
    };
    auto stageA = [&](int buf, int kt) {
        // load 16 fp32 of x, cvt to bf16, write two swizzled 16B LDS slots
        const float* xa = x + (size_t)(row0 + ar) * DD + kt * BK + ac;
        float fl[16];
        *(f32x4*)&fl[0]  = ((const f32x4*)xa)[0];
        *(f32x4*)&fl[4]  = ((const f32x4*)xa)[1];
        *(f32x4*)&fl[8]  = ((const f32x4*)xa)[2];
        *(f32x4*)&fl[12] = ((const f32x4*)xa)[3];
        ushort us[16];
        #pragma unroll
        for (int j = 0; j < 16; ++j) {
            __hip_bfloat16 bh = __float2bfloat16(fl[j]);
            us[j] = *(ushort*)&bh;
        }
        int s0 = ((t & 3) * 2)     ^ (ar & 7);
        int s1 = ((t & 3) * 2 + 1) ^ (ar & 7);
        *(ushort8*)&ldsA[buf][ar * 64 + s0 * 8] = *(ushort8*)&us[0];
        *(ushort8*)&ldsA[buf][ar * 64 + s1 * 8] = *(ushort8*)&us[8];
    };

    const int wm = (wave >> 1) * 32;   // wave row offset within 64-row tile
    const int wn = (wave & 1) * 64;    // wave col offset within 128-col tile
    const int l15 = lane & 15, l4 = lane >> 4;
    f32x4 acc[2][4] = {};

    stageB(0, 0);
    stageA(0, 0);
    __syncthreads();
    int cur = 0;
    #pragma unroll 1
    for (int kt = 0; kt < DD / BK; ++kt) {
        if (kt + 1 < DD / BK) stageB(cur ^ 1, kt + 1);

        // ---- LR gather: 16 frames for this step (latency hides under frags+MFMA) ----
        const int rb0 = chunk0 + kt * 16 + lr_half;
        int idxs[8];
        #pragma unroll
        for (int p = 0; p < 8; ++p) idxs[p] = imb[rb0 + p * 2];
        f32x4 gv[8];
        #pragma unroll
        for (int p = 0; p < 8; ++p)
            gv[p] = (idxs[p] >= 0) ? x4g[(size_t)idxs[p] * (DD / 4) + lr_lane]
                                   : (f32x4){0.f, 0.f, 0.f, 0.f};

        const ushort* At = &ldsA[cur][0];
        const ushort* Bt = &ldsB[cur][0];
        bf16x8 a[2][2], b[4][2];
        #pragma unroll
        for (int i = 0; i < 2; ++i) {
            int r = wm + i * 16 + l15;
            #pragma unroll
            for (int ks = 0; ks < 2; ++ks) {
                int sl = (ks * 4 + l4) ^ (r & 7);
                a[i][ks] = *(const bf16x8*)&At[r * 64 + sl * 8];
            }
        }
        #pragma unroll
        for (int j = 0; j < 4; ++j) {
            int r = wn + j * 16 + l15;
            #pragma unroll
            for (int ks = 0; ks < 2; ++ks) {
                int sl = (ks * 4 + l4) ^ (r & 7);
                b[j][ks] = *(const bf16x8*)&Bt[r * 64 + sl * 8];
            }
        }
        #pragma unroll
        for (int ks = 0; ks < 2; ++ks)
            #pragma unroll
            for (int i = 0; i < 2; ++i)
                #pragma unroll
                for (int j = 0; j < 4; ++j)
                    acc[i][j] = __builtin_amdgcn_mfma_f32_16x16x32_bf16(a[i][ks], b[j][ks], acc[i][j], 0, 0, 0);

        // ---- A-tile for next step: cvt + swizzled ds_write into buf^1 ----
        if (kt + 1 < DD / BK) stageA(cur ^ 1, kt + 1);

        // ---- LR store (nontemporal: pure stream, keep L2 for x/wth) ----
        #pragma unroll
        for (int p = 0; p < 8; ++p)
            __builtin_nontemporal_store(gv[p], &o4[(size_t)(rb0 + p * 2) * (DD / 4) + lr_lane]);

        __syncthreads();
        cur ^= 1;
    }

    // epilogue: relu(acc + b1) dot W2; partial slice = col-block*2 + col-half
    const int pslice = (bid & 3) * 2 + (wn >> 6);
    #pragma unroll
    for (int i = 0; i < 2; ++i) {
        #pragma unroll
        for (int r = 0; r < 4; ++r) {
            float s = 0.f;
            #pragma unroll
            for (int j = 0; j < 4; ++j) {
                int cg = col0 + wn + j * 16 + l15;
                float h = acc[i][j][r] + b1[cg];
                h = fmaxf(h, 0.f);
                s += h * W2[cg];
            }
            s += __shfl_xor(s, 1);
            s += __shfl_xor(s, 2);
            s += __shfl_xor(s, 4);
            s += __shfl_xor(s, 8);
            if (l15 == 0) {
                int rg = row0 + wm + i * 16 + l4 * 4 + r;
                partial[(size_t)pslice * MM + rg] = s;
            }
        }
    }
}

// ---------------- final dpo: relu(sum of 8 partials + b2) ----------------
__global__ __launch_bounds__(256) void dpo_kernel(const float* __restrict__ partial,
                                                  const float* __restrict__ b2,
                                                  float* __restrict__ dpo) {
    int m = blockIdx.x * 256 + threadIdx.x;
    float s = b2[0];
    #pragma unroll
    for (int nb = 0; nb < NPART; ++nb) s += partial[(size_t)nb * MM + m];
    dpo[m] = fmaxf(s, 0.f);
}

extern "C" void kernel_launch(void* const* d_in, const int* in_sizes, int n_in,
                              void* d_out, int out_size, void* d_ws, size_t ws_size,
                              hipStream_t stream) {
    const float* x      = (const float*)d_in[0];
    const float* W1     = (const float*)d_in[1];
    const float* b1     = (const float*)d_in[2];
    const float* W2     = (const float*)d_in[3];
    const float* b2     = (const float*)d_in[4];
    const int*   target = (const int*)d_in[5];
    int L = (out_size - BSZ * TT) / (BSZ * DD);   // = 4096

    float* out_lr  = (float*)d_out;                        // [B, L, D]
    float* out_dpo = (float*)d_out + (size_t)BSZ * L * DD; // [B, T]

    // ws layout
    ushort* wth     = (ushort*)d_ws;                        // 512 KiB
    float*  partial = (float*)(wth + (size_t)DD * DD);      // 8*8192 floats
    int*    imap    = (int*)(partial + (size_t)NPART * MM); // 16*4096 ints

    prep_kernel<<<dim3(272), dim3(256), 0, stream>>>(W1, target, wth, imap, L);
    mega_kernel<<<dim3(NMEGA), dim3(256), 0, stream>>>(wth, b1, W2, x, imap,
                                                       out_lr, partial, L);
    dpo_kernel<<<dim3(MM / 256), dim3(256), 0, stream>>>(partial, b2, out_dpo);
}